// Round 7
// baseline (920.670 us; speedup 1.0000x reference)
//
#include <hip/hip_runtime.h>

// k-means cluster step: N=400000, D=256, K=50 (fp32 in/out).
// TWO-PASS design: rounds 2-6 proved the fused (MFMA + register-payload
// scatter) kernel cannot get a spill-free allocation (allocator pins 64
// VGPRs and round-trips ~118MB through scratch). Splitting removes the
// need for any large live set:
//   A) assign:  scores=X*C^T via mfma_f32_16x16x32_f16, transient a-frags
//      (live ~50 VGPR), writes best-cluster index per point (1.6 MB).
//   B) scatter: re-reads x (octet layout, named float4 regs, ~45 VGPR),
//      LDS-atomic accumulate into padded sums, per-block partials.
//   C) reduce:  sum partials -> out.
// Total HBM ~840MB => ~135us floor; both kernels individually latency-safe.

typedef _Float16 f16x8 __attribute__((ext_vector_type(8)));
typedef float    f32x4 __attribute__((ext_vector_type(4)));

constexpr int K     = 50;
constexpr int KP    = 64;     // padded centroid count (4 n-tiles of 16)
constexpr int D     = 256;
constexpr int SROW  = 257;    // padded fp32 sums stride
constexpr int OUT_N = K * D + K;   // 12850
constexpr int BLK_A = 256;
constexpr int GRID_A = 1024;  // 4 blocks/CU (33KB LDS each) = 16 waves/CU
constexpr int BLK_B = 512;
constexpr int GRID_B = 512;   // 2 blocks/CU (51.6KB LDS each) = 16 waves/CU

// ---------------------------------------------------------------- assign ---
// C staged in LDS as f16, flat row stride 256 (512B) with XOR chunk swizzle:
// 16B chunk j of row r lives at chunk (j ^ (r&7)). b128 read of (nt,ks)
// then lands 64 lanes evenly 8-per-bank-quad = the 8-beat floor (optimal).
__global__ __launch_bounds__(BLK_A)
void kmeans_assign_idx(const float* __restrict__ x, const float* __restrict__ c,
                       int* __restrict__ idx, int N) {
    __shared__ _Float16 s_C[KP * D];   // 32768 B
    __shared__ float    s_c2[KP];

    const int tid = threadIdx.x;
    for (int i = tid; i < KP * D; i += BLK_A) s_C[i] = (_Float16)0.f;
    __syncthreads();
    for (int i = tid; i < K * D; i += BLK_A) {
        int r = i >> 8, col = i & 255;
        int ch = col >> 3, w = col & 7;
        s_C[r * D + (((ch ^ (r & 7)) << 3) | w)] = (_Float16)c[i];
    }
    if (tid < KP) {
        float s = 0.f;
        if (tid < K) {
            const float4* cr = (const float4*)(c + tid * D);
            for (int i = 0; i < D / 4; ++i) {
                float4 v = cr[i];
                s += v.x * v.x + v.y * v.y + v.z * v.z + v.w * v.w;
            }
        }
        s_c2[tid] = s;
    }
    __syncthreads();

    const int lane = tid & 63;
    const int ci   = lane & 15;   // A-row within tile / D-column
    const int g    = lane >> 4;   // k-chunk group
    const int cim  = ci & 7;      // swizzle key (row&7, same for all nt)
    const int wave = blockIdx.x * (BLK_A / 64) + (tid >> 6);
    const int nWaves = gridDim.x * (BLK_A / 64);
    const int nTiles = (N + 15) >> 4;

    const float INF = 3.4e38f;
    float c2v0 = (ci      < K) ? s_c2[ci]      : INF;
    float c2v1 = (16 + ci < K) ? s_c2[16 + ci] : INF;
    float c2v2 = (32 + ci < K) ? s_c2[32 + ci] : INF;
    float c2v3 = (48 + ci < K) ? s_c2[48 + ci] : INF;

    for (int t = wave; t < nTiles; t += nWaves) {
        const int row = t * 16 + ci;
        const bool rv = row < N;
        const float* xb = x + (size_t)row * D;
        const float4 z4{0.f, 0.f, 0.f, 0.f};

        f32x4 acc0{0,0,0,0}, acc1{0,0,0,0}, acc2{0,0,0,0}, acc3{0,0,0,0};

        // Transient a-frag per k-step: load 32B, cvt, 4 MFMAs, dead.
        // Live set stays ~50 VGPRs -> no spill at the default 64 budget.
#define KSTEP(ks) { \
        float4 u = rv ? *(const float4*)(xb + ks * 32 + g * 8)     : z4; \
        float4 v = rv ? *(const float4*)(xb + ks * 32 + g * 8 + 4) : z4; \
        f16x8 a = {(_Float16)u.x, (_Float16)u.y, (_Float16)u.z, (_Float16)u.w, \
                   (_Float16)v.x, (_Float16)v.y, (_Float16)v.z, (_Float16)v.w}; \
        const int chs = (((ks) << 2) | g) ^ cim; \
        { f16x8 bb = *(const f16x8*)(&s_C[(0 * 16 + ci) * D + (chs << 3)]); \
          acc0 = __builtin_amdgcn_mfma_f32_16x16x32_f16(a, bb, acc0, 0, 0, 0); } \
        { f16x8 bb = *(const f16x8*)(&s_C[(1 * 16 + ci) * D + (chs << 3)]); \
          acc1 = __builtin_amdgcn_mfma_f32_16x16x32_f16(a, bb, acc1, 0, 0, 0); } \
        { f16x8 bb = *(const f16x8*)(&s_C[(2 * 16 + ci) * D + (chs << 3)]); \
          acc2 = __builtin_amdgcn_mfma_f32_16x16x32_f16(a, bb, acc2, 0, 0, 0); } \
        { f16x8 bb = *(const f16x8*)(&s_C[(3 * 16 + ci) * D + (chs << 3)]); \
          acc3 = __builtin_amdgcn_mfma_f32_16x16x32_f16(a, bb, acc3, 0, 0, 0); } }
        KSTEP(0) KSTEP(1) KSTEP(2) KSTEP(3) KSTEP(4) KSTEP(5) KSTEP(6) KSTEP(7)
#undef KSTEP

        // argmin per point-row r (point = 4g+r): local over 4 cols, then
        // 16-lane butterfly with first-min (smallest k) tie-break.
        int b0, b1, b2, b3;
#define ARGMIN(r, OUTB) { \
        float m = c2v0 - 2.f * acc0[r]; int bi = ci; \
        { float s = c2v1 - 2.f * acc1[r]; if (s < m) { m = s; bi = 16 + ci; } } \
        { float s = c2v2 - 2.f * acc2[r]; if (s < m) { m = s; bi = 32 + ci; } } \
        { float s = c2v3 - 2.f * acc3[r]; if (s < m) { m = s; bi = 48 + ci; } } \
        { float pm; int pb; \
          pm = __shfl_xor(m, 1, 64); pb = __shfl_xor(bi, 1, 64); \
          if (pm < m || (pm == m && pb < bi)) { m = pm; bi = pb; } \
          pm = __shfl_xor(m, 2, 64); pb = __shfl_xor(bi, 2, 64); \
          if (pm < m || (pm == m && pb < bi)) { m = pm; bi = pb; } \
          pm = __shfl_xor(m, 4, 64); pb = __shfl_xor(bi, 4, 64); \
          if (pm < m || (pm == m && pb < bi)) { m = pm; bi = pb; } \
          pm = __shfl_xor(m, 8, 64); pb = __shfl_xor(bi, 8, 64); \
          if (pm < m || (pm == m && pb < bi)) { m = pm; bi = pb; } } \
        OUTB = bi; }
        ARGMIN(0, b0) ARGMIN(1, b1) ARGMIN(2, b2) ARGMIN(3, b3)
#undef ARGMIN

        if (ci < 4) {
            const int p = t * 16 + 4 * g + ci;
            if (p < N) {
                const int best = (ci == 0) ? b0 : (ci == 1) ? b1
                               : (ci == 2) ? b2 : b3;
                idx[p] = best;
            }
        }
    }
}

// --------------------------------------------------------------- scatter ---
__global__ __launch_bounds__(BLK_B)
void kmeans_scatter(const float* __restrict__ x, const int* __restrict__ idx,
                    float* __restrict__ partial, float* __restrict__ out,
                    int N, int useAtomic) {
    __shared__ float s_sums[K * SROW];  // 51400 B
    __shared__ int   s_cnt[K];

    const int tid = threadIdx.x;
    for (int i = tid; i < K * SROW; i += BLK_B) s_sums[i] = 0.f;
    if (tid < K) s_cnt[tid] = 0;
    __syncthreads();

    const int lane = tid & 63;
    const int o    = lane & 7;   // chunk owner within point
    const int g    = lane >> 3;  // point within group of 8
    const int wave = blockIdx.x * (BLK_B / 64) + (tid >> 6);
    const int nWaves  = gridDim.x * (BLK_B / 64);
    const int nGroups = (N + 7) >> 3;

    for (int pg = wave; pg < nGroups; pg += nWaves) {
        const int p = pg * 8 + g;
        const bool valid = (p < N);
        const float* xb = x + (size_t)p * D;
        const float4 z4{0.f, 0.f, 0.f, 0.f};

        float4 xr0 = valid ? *(const float4*)(xb + 32 * 0 + 4 * o) : z4;
        float4 xr1 = valid ? *(const float4*)(xb + 32 * 1 + 4 * o) : z4;
        float4 xr2 = valid ? *(const float4*)(xb + 32 * 2 + 4 * o) : z4;
        float4 xr3 = valid ? *(const float4*)(xb + 32 * 3 + 4 * o) : z4;
        float4 xr4 = valid ? *(const float4*)(xb + 32 * 4 + 4 * o) : z4;
        float4 xr5 = valid ? *(const float4*)(xb + 32 * 5 + 4 * o) : z4;
        float4 xr6 = valid ? *(const float4*)(xb + 32 * 6 + 4 * o) : z4;
        float4 xr7 = valid ? *(const float4*)(xb + 32 * 7 + 4 * o) : z4;

        const int best = valid ? idx[p] : 0;

        if (valid) {
            if (o == 0) atomicAdd(&s_cnt[best], 1);
            float* sr = &s_sums[best * SROW + 4 * o];
#define SCAT(i) { \
            atomicAdd(&sr[32 * i + 0], xr##i.x); \
            atomicAdd(&sr[32 * i + 1], xr##i.y); \
            atomicAdd(&sr[32 * i + 2], xr##i.z); \
            atomicAdd(&sr[32 * i + 3], xr##i.w); }
            SCAT(0) SCAT(1) SCAT(2) SCAT(3) SCAT(4) SCAT(5) SCAT(6) SCAT(7)
#undef SCAT
        }
    }
    __syncthreads();

    if (useAtomic) {
        for (int i = tid; i < K * D; i += BLK_B) {
            int k = i >> 8, d = i & 255;
            atomicAdd(&out[i], s_sums[k * SROW + d]);
        }
        for (int k2 = tid; k2 < K; k2 += BLK_B)
            atomicAdd(&out[K * D + k2], (float)s_cnt[k2]);
    } else {
        float* pb = partial + (size_t)blockIdx.x * OUT_N;
        for (int i = tid; i < K * D; i += BLK_B) {
            int k = i >> 8, d = i & 255;
            pb[i] = s_sums[k * SROW + d];
        }
        for (int k2 = tid; k2 < K; k2 += BLK_B)
            pb[K * D + k2] = (float)s_cnt[k2];
    }
}

// ---------------------------------------------------------------- reduce ---
__global__ void kmeans_reduce(const float* __restrict__ partial,
                              float* __restrict__ out, int G) {
    int j = blockIdx.x * blockDim.x + threadIdx.x;
    if (j >= OUT_N) return;
    float s = 0.f;
    for (int b = 0; b < G; ++b) s += partial[(size_t)b * OUT_N + j];
    out[j] = s;
}

// ---------------------------------------------------------------- launch ---
extern "C" void kernel_launch(void* const* d_in, const int* in_sizes, int n_in,
                              void* d_out, int out_size, void* d_ws, size_t ws_size,
                              hipStream_t stream) {
    const float* x = (const float*)d_in[0];
    const float* c = (const float*)d_in[1];
    float* out = (float*)d_out;
    const int N = in_sizes[0] / D;

    // d_ws layout: [idx: N ints][partials: GRID_B * OUT_N floats]
    const size_t idxBytes = ((size_t)N * sizeof(int) + 255) & ~(size_t)255;
    int*   idx     = (int*)d_ws;
    float* partial = (float*)((char*)d_ws + idxBytes);
    const size_t need = idxBytes + (size_t)GRID_B * OUT_N * sizeof(float);
    const int useAtomic = (ws_size < need) ? 1 : 0;

    kmeans_assign_idx<<<GRID_A, BLK_A, 0, stream>>>(x, c, idx, N);
    if (useAtomic) {
        hipMemsetAsync(d_out, 0, (size_t)out_size * sizeof(float), stream);
    }
    kmeans_scatter<<<GRID_B, BLK_B, 0, stream>>>(x, idx, partial, out, N, useAtomic);
    if (!useAtomic) {
        kmeans_reduce<<<(OUT_N + 255) / 256, 256, 0, stream>>>(
            (const float*)partial, out, GRID_B);
    }
}

// Round 8
// 269.437 us; speedup vs baseline: 3.4170x; 3.4170x over previous
//
#include <hip/hip_runtime.h>

// k-means cluster step: N=400000, D=256, K=50 (fp32 in/out).
// Three-kernel streaming design (round 7 showed: LDS atomics serialize
// ~1.6M wave-instrs -> 529us, and per-lane float4 streaming caps ~1TB/s):
//   1) k_assign : scores = X*C^T via mfma_16x16x32_f16; x staged chunk-wise
//      into LDS with global_load_lds (src-swizzled for conflict-free reads);
//      writes idx[p]. ~45 VGPR (fits the 64 budget -- no allocator fight).
//   2) k_scatter: sums = onehot(idx)^T * X as a second MFMA GEMM (no
//      atomics at all); per-block partials.
//   3) k_hist + k_reduce: counts histogram + partial reduction.

typedef _Float16 f16x8 __attribute__((ext_vector_type(8)));
typedef float    f32x4 __attribute__((ext_vector_type(4)));

constexpr int K  = 50, KP = 64, D = 256;
constexpr int KD = K * D;              // 12800
constexpr int A_BLK = 256,  A_GRID = 512, A_CH = 16;   // assign: 16-pt chunks
constexpr int S_BLK = 1024, S_GRID = 512, S_CH = 32;   // scatter: 32-pt chunks

#define AS_GLB(p) (const __attribute__((address_space(1))) void*)(p)
#define AS_LDS(p) (__attribute__((address_space(3))) void*)(p)

// 16-lane argmin butterfly, first-min (smallest index) tie-break
#define RED16(m, b) { float pm; int pb; \
    pm = __shfl_xor(m,1,64); pb = __shfl_xor(b,1,64); if (pm<m||(pm==m&&pb<b)){m=pm;b=pb;} \
    pm = __shfl_xor(m,2,64); pb = __shfl_xor(b,2,64); if (pm<m||(pm==m&&pb<b)){m=pm;b=pb;} \
    pm = __shfl_xor(m,4,64); pb = __shfl_xor(b,4,64); if (pm<m||(pm==m&&pb<b)){m=pm;b=pb;} \
    pm = __shfl_xor(m,8,64); pb = __shfl_xor(b,8,64); if (pm<m||(pm==m&&pb<b)){m=pm;b=pb;} }

// ---------------------------------------------------------------- assign ---
__global__ __launch_bounds__(A_BLK)
void k_assign(const float* __restrict__ x, const float* __restrict__ c,
              int* __restrict__ idx, int N) {
    __shared__ _Float16 sC[KP * D];        // 32KB, chunk-XOR swizzled (v7)
    __shared__ float    sc2[KP];
    __shared__ float    sx[2][A_CH * D];   // 2 x 16KB, src-swizzled staging
    __shared__ float    sredm[4][16];
    __shared__ int      sredb[4][16];

    const int tid = threadIdx.x;
    for (int i = tid; i < KP * D; i += A_BLK) sC[i] = (_Float16)0.f;
    __syncthreads();
    for (int i = tid; i < K * D; i += A_BLK) {
        int r = i >> 8, col = i & 255, ch = col >> 3, wd = col & 7;
        sC[r * D + (((ch ^ (r & 7)) << 3) | wd)] = (_Float16)c[i];
    }
    if (tid < KP) {
        float s = 0.f;
        if (tid < K) for (int i = 0; i < D; ++i) { float v = c[tid * D + i]; s += v * v; }
        sc2[tid] = s;
    }
    __syncthreads();

    const int lane = tid & 63, ci = lane & 15, g = lane >> 4, w = tid >> 6;
    const int nCh = N / A_CH;
    const int cpb = nCh / gridDim.x, rem = nCh % gridDim.x;
    const int bid = blockIdx.x;
    const int lo  = bid * cpb + (bid < rem ? bid : rem);
    const int cnt = cpb + (bid < rem ? 1 : 0);

    // stage chunk t into sx[buf]: dest chunk16B (p, lane) holds src chunk
    // (lane ^ (p&7)) of row p  -> a-frag b128 reads land 2-way-conflict (free)
#define A_STAGE(buf, t) { \
    const float* base_ = x + (size_t)(t) * (A_CH * D); \
    _Pragma("unroll") for (int q = 0; q < 4; ++q) { \
        const int p_ = q * 4 + w; \
        const float* src_ = base_ + p_ * D + ((lane ^ (p_ & 7)) << 2); \
        char* dst_ = (char*)(&sx[buf][0]) + q * 4096 + w * 1024; \
        __builtin_amdgcn_global_load_lds(AS_GLB(src_), AS_LDS(dst_), 16, 0, 0); } }

    const float INF = 3.4e38f;
    const int   myc = w * 16 + ci;                  // this lane's cluster col
    const float c2v = (myc < K) ? sc2[myc] : INF;   // pad clusters masked

    if (cnt > 0) A_STAGE(0, lo);
    __syncthreads();
    int buf = 0;
    for (int i = 0; i < cnt; ++i) {
        const int t = lo + i;
        if (i + 1 < cnt) A_STAGE(buf ^ 1, t + 1);

        f32x4 acc = {0.f, 0.f, 0.f, 0.f};
        const float*    xb = &sx[buf][0];
        const _Float16* cb = &sC[myc * D];
        const int key = ci & 7;
#define A_KS(ks) { \
        f32x4 u0 = *(const f32x4*)(xb + ci * D + (((ks * 8 + 2 * g + 0) ^ key) << 2)); \
        f32x4 u1 = *(const f32x4*)(xb + ci * D + (((ks * 8 + 2 * g + 1) ^ key) << 2)); \
        f16x8 a = {(_Float16)u0[0], (_Float16)u0[1], (_Float16)u0[2], (_Float16)u0[3], \
                   (_Float16)u1[0], (_Float16)u1[1], (_Float16)u1[2], (_Float16)u1[3]}; \
        f16x8 bbv = *(const f16x8*)(cb + ((((ks) * 4 + g) ^ key) << 3)); \
        acc = __builtin_amdgcn_mfma_f32_16x16x32_f16(a, bbv, acc, 0, 0, 0); }
        A_KS(0) A_KS(1) A_KS(2) A_KS(3) A_KS(4) A_KS(5) A_KS(6) A_KS(7)
#undef A_KS

        // lane holds score[point 4g+r][cluster myc]; reduce over 16 ci-lanes
        float m0 = c2v - 2.f * acc[0]; int b0 = myc;
        float m1 = c2v - 2.f * acc[1]; int b1 = myc;
        float m2 = c2v - 2.f * acc[2]; int b2 = myc;
        float m3 = c2v - 2.f * acc[3]; int b3 = myc;
        RED16(m0, b0) RED16(m1, b1) RED16(m2, b2) RED16(m3, b3)
        if (ci == 0) {
            sredm[w][4 * g + 0] = m0; sredb[w][4 * g + 0] = b0;
            sredm[w][4 * g + 1] = m1; sredb[w][4 * g + 1] = b1;
            sredm[w][4 * g + 2] = m2; sredb[w][4 * g + 2] = b2;
            sredm[w][4 * g + 3] = m3; sredb[w][4 * g + 3] = b3;
        }
        __syncthreads();   // also drains stage(t+1) -> ready next iter
        if (tid < 16) {
            float bm = sredm[0][tid]; int bbk = sredb[0][tid];
            for (int w2 = 1; w2 < 4; ++w2) {
                float mm = sredm[w2][tid]; int bi = sredb[w2][tid];
                if (mm < bm || (mm == bm && bi < bbk)) { bm = mm; bbk = bi; }
            }
            idx[t * A_CH + tid] = bbk;
        }
        __syncthreads();
        buf ^= 1;
    }
}

// --------------------------------------------------------------- scatter ---
// sums = onehot^T * X: D[cluster][dcol] += sum_k onehot[cl][pt_k]*x[pt_k][dcol]
__global__ __launch_bounds__(S_BLK)
void k_scatter(const float* __restrict__ x, const int* __restrict__ idxg,
               float* __restrict__ partial, float* __restrict__ out,
               int N, int useAtomic) {
    __shared__ float sx[2][S_CH * D];   // 2 x 32KB, src-swizzled
    __shared__ int   sidx[2][S_CH];

    const int tid = threadIdx.x;
    const int lane = tid & 63, ci = lane & 15, g = lane >> 4, w = tid >> 6;
    const int nCh = N / S_CH;
    const int cpb = nCh / gridDim.x, rem = nCh % gridDim.x;
    const int bid = blockIdx.x;
    const int lo  = bid * cpb + (bid < rem ? bid : rem);
    const int cnt = cpb + (bid < rem ? 1 : 0);

#define S_STAGE(buf, t) { \
    const float* base_ = x + (size_t)(t) * (S_CH * D); \
    _Pragma("unroll") for (int q = 0; q < 2; ++q) { \
        const int p_ = q * 16 + w; \
        const float* src_ = base_ + p_ * D + ((lane ^ (((p_ >> 3) & 1) << 2)) << 2); \
        char* dst_ = (char*)(&sx[buf][0]) + q * 16384 + w * 1024; \
        __builtin_amdgcn_global_load_lds(AS_GLB(src_), AS_LDS(dst_), 16, 0, 0); } \
    if (tid < 32) { \
        const int* isrc_ = idxg + (size_t)(t) * S_CH + tid; \
        char* idst_ = (char*)(&sidx[buf][0]); \
        __builtin_amdgcn_global_load_lds(AS_GLB(isrc_), AS_LDS(idst_), 4, 0, 0); } }

    f32x4 acc0 = {0,0,0,0}, acc1 = {0,0,0,0}, acc2 = {0,0,0,0}, acc3 = {0,0,0,0};

    if (cnt > 0) S_STAGE(0, lo);
    __syncthreads();
    int buf = 0;
    for (int i = 0; i < cnt; ++i) {
        if (i + 1 < cnt) S_STAGE(buf ^ 1, lo + i + 1);

        const float* xb = &sx[buf][0];
        const int c16 = (w * 4 + (ci >> 2)) ^ ((g & 1) << 2);  // swizzled chunk
        const int e   = (ci & 3);
#define RD(j) xb[(8 * g + j) * D + (c16 << 2) + e]
        float f0 = RD(0), f1 = RD(1), f2 = RD(2), f3 = RD(3);
        float f4 = RD(4), f5 = RD(5), f6 = RD(6), f7 = RD(7);
#undef RD
        f16x8 bbv = {(_Float16)f0, (_Float16)f1, (_Float16)f2, (_Float16)f3,
                     (_Float16)f4, (_Float16)f5, (_Float16)f6, (_Float16)f7};
        const int i0 = sidx[buf][8 * g + 0], i1 = sidx[buf][8 * g + 1];
        const int i2 = sidx[buf][8 * g + 2], i3 = sidx[buf][8 * g + 3];
        const int i4 = sidx[buf][8 * g + 4], i5 = sidx[buf][8 * g + 5];
        const int i6 = sidx[buf][8 * g + 6], i7 = sidx[buf][8 * g + 7];
#define AMT(mt, ACC) { \
        const int cl_ = mt * 16 + ci; \
        f16x8 a = {(_Float16)(i0 == cl_ ? 1.f : 0.f), (_Float16)(i1 == cl_ ? 1.f : 0.f), \
                   (_Float16)(i2 == cl_ ? 1.f : 0.f), (_Float16)(i3 == cl_ ? 1.f : 0.f), \
                   (_Float16)(i4 == cl_ ? 1.f : 0.f), (_Float16)(i5 == cl_ ? 1.f : 0.f), \
                   (_Float16)(i6 == cl_ ? 1.f : 0.f), (_Float16)(i7 == cl_ ? 1.f : 0.f)}; \
        ACC = __builtin_amdgcn_mfma_f32_16x16x32_f16(a, bbv, ACC, 0, 0, 0); }
        AMT(0, acc0) AMT(1, acc1) AMT(2, acc2) AMT(3, acc3)
#undef AMT
        __syncthreads();
        buf ^= 1;
    }

    // D layout: col = ci (wave's 16-col tile w), row = 4g + r (cluster in mt)
    const int col = w * 16 + ci;
#define WB(mt, ACC, DST, ATOMIC) { \
    { int cl_ = mt * 16 + 4 * g + 0; if (cl_ < K) { if (ATOMIC) atomicAdd(&DST[cl_ * D + col], ACC[0]); else DST[cl_ * D + col] = ACC[0]; } } \
    { int cl_ = mt * 16 + 4 * g + 1; if (cl_ < K) { if (ATOMIC) atomicAdd(&DST[cl_ * D + col], ACC[1]); else DST[cl_ * D + col] = ACC[1]; } } \
    { int cl_ = mt * 16 + 4 * g + 2; if (cl_ < K) { if (ATOMIC) atomicAdd(&DST[cl_ * D + col], ACC[2]); else DST[cl_ * D + col] = ACC[2]; } } \
    { int cl_ = mt * 16 + 4 * g + 3; if (cl_ < K) { if (ATOMIC) atomicAdd(&DST[cl_ * D + col], ACC[3]); else DST[cl_ * D + col] = ACC[3]; } } }
    if (useAtomic) {
        WB(0, acc0, out, 1) WB(1, acc1, out, 1) WB(2, acc2, out, 1) WB(3, acc3, out, 1)
    } else {
        float* pb = partial + (size_t)bid * KD;
        WB(0, acc0, pb, 0) WB(1, acc1, pb, 0) WB(2, acc2, pb, 0) WB(3, acc3, pb, 0)
    }
#undef WB
}

// ----------------------------------------------------------- hist/reduce ---
__global__ __launch_bounds__(256)
void k_hist(const int* __restrict__ idxg, float* __restrict__ out, int N) {
    __shared__ int h[K];
    const int tid = threadIdx.x;
    if (tid < K) h[tid] = 0;
    __syncthreads();
    for (int i = blockIdx.x * 256 + tid; i < N; i += gridDim.x * 256)
        atomicAdd(&h[idxg[i]], 1);
    __syncthreads();
    if (tid < K) atomicAdd(&out[KD + tid], (float)h[tid]);
}

__global__ __launch_bounds__(256)
void k_reduce(const float* __restrict__ partial, float* __restrict__ out, int G) {
    const int j  = blockIdx.x * 256 + threadIdx.x;    // < KD
    const int bs = G / 8;
    const int b0 = blockIdx.y * bs;
    float s = 0.f;
    for (int b = b0; b < b0 + bs; ++b) s += partial[(size_t)b * KD + j];
    atomicAdd(&out[j], s);
}

// ---------------------------------------------------------------- launch ---
extern "C" void kernel_launch(void* const* d_in, const int* in_sizes, int n_in,
                              void* d_out, int out_size, void* d_ws, size_t ws_size,
                              hipStream_t stream) {
    const float* x = (const float*)d_in[0];
    const float* c = (const float*)d_in[1];
    float* out = (float*)d_out;
    const int N = in_sizes[0] / D;

    const size_t idxBytes = ((size_t)N * sizeof(int) + 255) & ~(size_t)255;
    int*   idx     = (int*)d_ws;
    float* partial = (float*)((char*)d_ws + idxBytes);
    const size_t need = idxBytes + (size_t)S_GRID * KD * sizeof(float);
    const int useAtomic = (ws_size < need) ? 1 : 0;

    hipMemsetAsync(d_out, 0, (size_t)out_size * sizeof(float), stream);
    k_assign<<<A_GRID, A_BLK, 0, stream>>>(x, c, idx, N);
    k_scatter<<<S_GRID, S_BLK, 0, stream>>>(x, idx, partial, out, N, useAtomic);
    k_hist<<<256, 256, 0, stream>>>(idx, out, N);
    if (!useAtomic) {
        k_reduce<<<dim3(KD / 256, 8), 256, 0, stream>>>(partial, out, S_GRID);
    }
}